// Round 5
// baseline (1191.562 us; speedup 1.0000x reference)
//
#include <hip/hip_runtime.h>
#include <math.h>

// ---------------------------------------------------------------------------
// HGCN, 2 layers. softmax over size-1 axis == 1.0 -> attention branch dead.
//   Y = X@W + b  (bf16 MFMA, fp32 accum, bf16 store)
//   agg[n] = -|curv| * (Y[n] + sum_{dst(e)=n} Y[src(e)])
//   layer1 -> relu (bf16 h), layer2 -> log_softmax (fp32 out)
// 5 dispatches:
//   S0 prep: weight transpose->bf16, zero rangeLen
//   S1 scatter(196 blk) || gemm1(782 blk): edges bucketed into 196 fixed-cap
//      range slabs (packed ldst<<16|src), Y1 computed
//   S2 agg1 (range x colhalf = 392 blk): LDS fp32 scatter-accumulate + relu
//   S3 gemm2 (782 blk)
//   S4 agg2 (196 blk): LDS accumulate + fused log_softmax
// ---------------------------------------------------------------------------

#define NRANGE 196            // ceil(50000/256) node ranges of 256
#define RCAP   4608           // slab capacity; mean 4096, std 64 -> +8 sigma

typedef float f32x4 __attribute__((ext_vector_type(4)));
typedef short bf16x8 __attribute__((ext_vector_type(8)));

__device__ inline ushort f2bf(float x) {
    unsigned u = __float_as_uint(x);
    return (ushort)((u + 0x7fffu + ((u >> 16) & 1u)) >> 16);
}
__device__ inline unsigned f2bf_pack(float a, float b) {
    return (unsigned)f2bf(a) | ((unsigned)f2bf(b) << 16);
}
__device__ inline float bflo(unsigned u) { return __uint_as_float(u << 16); }
__device__ inline float bfhi(unsigned u) { return __uint_as_float(u & 0xffff0000u); }

// ---------------- S0: weight prep + rangeLen zero --------------------------
__launch_bounds__(256)
__global__ void prep_kernel(const float* __restrict__ W1, const float* __restrict__ W2,
                            ushort* __restrict__ Wt1, ushort* __restrict__ Wt2,
                            int* __restrict__ rangeLen) {
    if (blockIdx.x == 0 && threadIdx.x < NRANGE) rangeLen[threadIdx.x] = 0;
    int t = blockIdx.x * 256 + threadIdx.x;
    if (t < 16384) {               // Wt1[c][k] = bf16(W1[k][c]), 128x128
        int c = t >> 7, k = t & 127;
        Wt1[t] = f2bf(W1[k * 128 + c]);
    } else if (t < 24576) {        // Wt2[c][k] = bf16(W2[k][c]), 64x128
        int i = t - 16384;
        int c = i >> 7, k = i & 127;
        Wt2[i] = f2bf(W2[k * 64 + c]);
    }
}

// ---------------- S1: fused edge-bucket scatter || gemm1 -------------------
__launch_bounds__(256)
__global__ void stage1_kernel(const int* __restrict__ src, const int* __restrict__ dst,
                              int* __restrict__ rangeLen, unsigned* __restrict__ ebuf, int E,
                              int scatterBlocks,
                              const float* __restrict__ X, const ushort* __restrict__ Wt,
                              const float* __restrict__ Bb, ushort* __restrict__ Y, int nrows) {
    __shared__ uint4 As[1024];            // gemm path (16 KB)
    __shared__ int sh_h[NRANGE];          // scatter path
    __shared__ int sh_base[NRANGE];
    const int t = threadIdx.x;

    if ((int)blockIdx.x < scatterBlocks) {
        // ---- edge bucket scatter: 4096 edges per block ----
        if (t < NRANGE) sh_h[t] = 0;
        __syncthreads();
        const int cbase = blockIdx.x * 4096;
        for (int i = t; i < 4096; i += 256) {
            int e = cbase + i;
            if (e < E) atomicAdd(&sh_h[dst[e] >> 8], 1);
        }
        __syncthreads();
        if (t < NRANGE) {
            int c = sh_h[t];
            sh_base[t] = c ? atomicAdd(&rangeLen[t], c) : 0;
            sh_h[t] = 0;
        }
        __syncthreads();
        for (int i = t; i < 4096; i += 256) {
            int e = cbase + i;
            if (e < E) {
                int d = dst[e];
                int r = d >> 8;
                int slot = sh_base[r] + atomicAdd(&sh_h[r], 1);
                ebuf[(size_t)r * RCAP + slot] = (unsigned)src[e] | ((unsigned)(d & 255) << 16);
            }
        }
        return;
    }

    // ---- gemm1: Y[64 rows x 128 cols] = bf16(X @ W1 + b1) ----
    const int rowBase = ((int)blockIdx.x - scatterBlocks) * 64;
#pragma unroll
    for (int i = 0; i < 4; ++i) {
        int s = i * 256 + t;
        int r = s >> 4, kb = s & 15;
        int grow = rowBase + r;
        float4 f0 = make_float4(0.f,0.f,0.f,0.f), f1 = f0;
        if (grow < nrows) {
            const float4* xp = (const float4*)(X + (size_t)grow * 128 + kb * 8);
            f0 = xp[0]; f1 = xp[1];
        }
        uint4 u;
        u.x = f2bf_pack(f0.x, f0.y); u.y = f2bf_pack(f0.z, f0.w);
        u.z = f2bf_pack(f1.x, f1.y); u.w = f2bf_pack(f1.z, f1.w);
        As[r * 16 + (kb ^ (r & 15))] = u;
    }
    __syncthreads();
    const int lane = t & 63, w = t >> 6;
    const int row = w * 16 + (lane & 15);
    const int lg = lane >> 4;
    f32x4 acc[8];
#pragma unroll
    for (int tc = 0; tc < 8; ++tc) acc[tc] = (f32x4){0.f, 0.f, 0.f, 0.f};
    const uint4* Wv = (const uint4*)Wt;
#pragma unroll
    for (int ks = 0; ks < 4; ++ks) {
        int kb = ks * 4 + lg;
        bf16x8 a = *(const bf16x8*)&As[row * 16 + (kb ^ (row & 15))];
#pragma unroll
        for (int tc = 0; tc < 8; ++tc) {
            int col = tc * 16 + (lane & 15);
            bf16x8 b = *(const bf16x8*)&Wv[col * 16 + kb];
            acc[tc] = __builtin_amdgcn_mfma_f32_16x16x32_bf16(a, b, acc[tc], 0, 0, 0);
        }
    }
#pragma unroll
    for (int tc = 0; tc < 8; ++tc) {
        int col = tc * 16 + (lane & 15);
        float bias = Bb[col];
#pragma unroll
        for (int e = 0; e < 4; ++e) {
            int grow = rowBase + w * 16 + lg * 4 + e;
            if (grow < nrows) Y[(size_t)grow * 128 + col] = f2bf(acc[tc][e] + bias);
        }
    }
}

// ---------------- S3: gemm2 (standalone) -----------------------------------
__launch_bounds__(256)
__global__ void gemm2_kernel(const ushort* __restrict__ Hb, const ushort* __restrict__ Wt,
                             const float* __restrict__ Bb, ushort* __restrict__ Y, int nrows) {
    __shared__ uint4 As[1024];
    const int t = threadIdx.x;
    const int rowBase = blockIdx.x * 64;
    const uint4* Hv = (const uint4*)Hb;
#pragma unroll
    for (int i = 0; i < 4; ++i) {
        int s = i * 256 + t;
        int r = s >> 4, kb = s & 15;
        int grow = rowBase + r;
        uint4 u = make_uint4(0u, 0u, 0u, 0u);
        if (grow < nrows) u = Hv[(size_t)grow * 16 + kb];
        As[r * 16 + (kb ^ (r & 15))] = u;
    }
    __syncthreads();
    const int lane = t & 63, w = t >> 6;
    const int row = w * 16 + (lane & 15);
    const int lg = lane >> 4;
    f32x4 acc[4];
#pragma unroll
    for (int tc = 0; tc < 4; ++tc) acc[tc] = (f32x4){0.f, 0.f, 0.f, 0.f};
    const uint4* Wv = (const uint4*)Wt;
#pragma unroll
    for (int ks = 0; ks < 4; ++ks) {
        int kb = ks * 4 + lg;
        bf16x8 a = *(const bf16x8*)&As[row * 16 + (kb ^ (row & 15))];
#pragma unroll
        for (int tc = 0; tc < 4; ++tc) {
            int col = tc * 16 + (lane & 15);
            bf16x8 b = *(const bf16x8*)&Wv[col * 16 + kb];
            acc[tc] = __builtin_amdgcn_mfma_f32_16x16x32_bf16(a, b, acc[tc], 0, 0, 0);
        }
    }
#pragma unroll
    for (int tc = 0; tc < 4; ++tc) {
        int col = tc * 16 + (lane & 15);
        float bias = Bb[col];
#pragma unroll
        for (int e = 0; e < 4; ++e) {
            int grow = rowBase + w * 16 + lg * 4 + e;
            if (grow < nrows) Y[(size_t)grow * 64 + col] = f2bf(acc[tc][e] + bias);
        }
    }
}

// ---------------- S2: agg1 — LDS fp32 scatter-accumulate + relu ------------
// block = (range r, col-half). sh[256][65] fp32 accumulators (pad -> 2-way
// free banks). Init with self-rows, stream range edges, gather 128B half-rows
// (32 lanes x uint), ds_add_f32 into dst accumulator. Epilogue: scale+relu,
// pack bf16 to Hb.
__launch_bounds__(512)
__global__ void agg1_kernel(const unsigned* __restrict__ Yu,     // [N][64] uints
                            const unsigned* __restrict__ ebuf,
                            const int* __restrict__ rangeLen,
                            const float* __restrict__ curv,
                            unsigned* __restrict__ Hb,           // [N][64] uints
                            int nnodes) {
    __shared__ float sh[256][65];
    const int t = threadIdx.x;
    const int r = blockIdx.x % NRANGE;
    const int half = blockIdx.x / NRANGE;            // 0 or 1
    const int nbase = r << 8;
    const int nn = min(256, nnodes - nbase);

    for (int i = t; i < 256 * 32; i += 512) {        // init: self rows / zeros
        int n = i >> 5, l = i & 31;
        float v0 = 0.f, v1 = 0.f;
        if (n < nn) {
            unsigned u = Yu[(size_t)(nbase + n) * 64 + half * 32 + l];
            v0 = bflo(u); v1 = bfhi(u);
        }
        sh[n][2 * l] = v0; sh[n][2 * l + 1] = v1;
    }
    __syncthreads();

    const int cnt = rangeLen[r];
    const unsigned* eb = ebuf + (size_t)r * RCAP;
    const int wid = t >> 6, lane = t & 63;
    const int sub = lane >> 5, l2 = lane & 31;
    int i = wid * 2 + sub;                            // 16 edges per block-iter
    for (; i + 16 < cnt; i += 32) {                   // unroll 2 (2 gathers in flight)
        unsigned pA = eb[i], pB = eb[i + 16];
        unsigned uA = Yu[(size_t)(pA & 0xFFFFu) * 64 + half * 32 + l2];
        unsigned uB = Yu[(size_t)(pB & 0xFFFFu) * 64 + half * 32 + l2];
        int dA = pA >> 16, dB = pB >> 16;
        atomicAdd(&sh[dA][2 * l2],     bflo(uA));
        atomicAdd(&sh[dA][2 * l2 + 1], bfhi(uA));
        atomicAdd(&sh[dB][2 * l2],     bflo(uB));
        atomicAdd(&sh[dB][2 * l2 + 1], bfhi(uB));
    }
    for (; i < cnt; i += 16) {
        unsigned p = eb[i];
        unsigned u = Yu[(size_t)(p & 0xFFFFu) * 64 + half * 32 + l2];
        int d = p >> 16;
        atomicAdd(&sh[d][2 * l2],     bflo(u));
        atomicAdd(&sh[d][2 * l2 + 1], bfhi(u));
    }
    __syncthreads();

    const float sc = -fabsf(curv[0]);
    for (int i2 = t; i2 < nn * 32; i2 += 512) {
        int n = i2 >> 5, l = i2 & 31;
        float a0 = fmaxf(sh[n][2 * l] * sc, 0.f);
        float a1 = fmaxf(sh[n][2 * l + 1] * sc, 0.f);
        Hb[(size_t)(nbase + n) * 64 + half * 32 + l] = f2bf_pack(a0, a1);
    }
}

// ---------------- S4: agg2 — LDS accumulate + fused log_softmax ------------
// block = range. Y2 rows are 64 cols (32 uints = 128B = one line per edge).
__launch_bounds__(512)
__global__ void agg2_kernel(const unsigned* __restrict__ Yu,     // [N][32] uints
                            const unsigned* __restrict__ ebuf,
                            const int* __restrict__ rangeLen,
                            const float* __restrict__ curv,
                            float* __restrict__ out,             // [N][64] fp32
                            int nnodes) {
    __shared__ float sh[256][65];
    const int t = threadIdx.x;
    const int r = blockIdx.x;
    const int nbase = r << 8;
    const int nn = min(256, nnodes - nbase);

    for (int i = t; i < 256 * 32; i += 512) {        // init: self rows / zeros
        int n = i >> 5, l = i & 31;
        float v0 = 0.f, v1 = 0.f;
        if (n < nn) {
            unsigned u = Yu[(size_t)(nbase + n) * 32 + l];
            v0 = bflo(u); v1 = bfhi(u);
        }
        sh[n][2 * l] = v0; sh[n][2 * l + 1] = v1;
    }
    __syncthreads();

    const int cnt = rangeLen[r];
    const unsigned* eb = ebuf + (size_t)r * RCAP;
    const int wid = t >> 6, lane = t & 63;
    const int sub = lane >> 5, l2 = lane & 31;
    int i = wid * 2 + sub;
    for (; i + 16 < cnt; i += 32) {
        unsigned pA = eb[i], pB = eb[i + 16];
        unsigned uA = Yu[(size_t)(pA & 0xFFFFu) * 32 + l2];
        unsigned uB = Yu[(size_t)(pB & 0xFFFFu) * 32 + l2];
        int dA = pA >> 16, dB = pB >> 16;
        atomicAdd(&sh[dA][2 * l2],     bflo(uA));
        atomicAdd(&sh[dA][2 * l2 + 1], bfhi(uA));
        atomicAdd(&sh[dB][2 * l2],     bflo(uB));
        atomicAdd(&sh[dB][2 * l2 + 1], bfhi(uB));
    }
    for (; i < cnt; i += 16) {
        unsigned p = eb[i];
        unsigned u = Yu[(size_t)(p & 0xFFFFu) * 32 + l2];
        int d = p >> 16;
        atomicAdd(&sh[d][2 * l2],     bflo(u));
        atomicAdd(&sh[d][2 * l2 + 1], bfhi(u));
    }
    __syncthreads();

    const float sc = -fabsf(curv[0]);
    for (int n = wid; n < nn; n += 8) {               // wave per node: log_softmax
        float a = sh[n][lane] * sc;
        float m = a;
#pragma unroll
        for (int d = 32; d; d >>= 1) m = fmaxf(m, __shfl_xor(m, d));
        float e = expf(a - m);
        float s = e;
#pragma unroll
        for (int d = 32; d; d >>= 1) s += __shfl_xor(s, d);
        out[(size_t)(nbase + n) * 64 + lane] = a - m - logf(s);
    }
}

// ---------------------------------------------------------------------------
extern "C" void kernel_launch(void* const* d_in, const int* in_sizes, int n_in,
                              void* d_out, int out_size, void* d_ws, size_t ws_size,
                              hipStream_t stream) {
    const float* x     = (const float*)d_in[0];
    const int*   ei    = (const int*)d_in[1];
    const float* W1    = (const float*)d_in[2];
    const float* b1    = (const float*)d_in[3];
    const float* curv1 = (const float*)d_in[6];
    const float* W2    = (const float*)d_in[7];
    const float* b2    = (const float*)d_in[8];
    const float* curv2 = (const float*)d_in[11];
    float* out = (float*)d_out;

    const int N = 50000;
    const int E = in_sizes[1] / 2;         // 800000
    const int* src = ei;
    const int* dst = ei + E;
    const int SB = (E + 4095) / 4096;      // 196 scatter blocks
    const int GB = (N + 63) / 64;          // 782 gemm blocks

    char* ws = (char*)d_ws;
    const size_t MB = 1024u * 1024u;
    ushort*   Y1b      = (ushort*)(ws);                    // bf16 [N,128] (reused as Y2 [N,64])
    ushort*   Hb       = (ushort*)(ws + 13 * MB);          // bf16 [N,128]
    unsigned* ebuf     = (unsigned*)(ws + 26 * MB);        // 196 * 4608 * 4B = 3.62 MB
    int*      rangeLen = (int*)(ws + 30 * MB);             // 196 ints
    ushort*   Wt1      = (ushort*)(ws + 30 * MB + 4096);   // 32 KB
    ushort*   Wt2      = (ushort*)(ws + 30 * MB + 4096 + 32768);  // 16 KB

    // S0: weight transpose + rangeLen zero
    prep_kernel<<<dim3(96), dim3(256), 0, stream>>>(W1, W2, Wt1, Wt2, rangeLen);

    // S1: edge bucket scatter || gemm1 (independent, one dispatch)
    stage1_kernel<<<dim3(SB + GB), dim3(256), 0, stream>>>(
        src, dst, rangeLen, ebuf, E, SB, x, Wt1, b1, Y1b, N);

    // S2: agg1 (+relu, bf16 h)
    agg1_kernel<<<dim3(2 * NRANGE), dim3(512), 0, stream>>>(
        (const unsigned*)Y1b, ebuf, rangeLen, curv1, (unsigned*)Hb, N);

    // S3: gemm2 (writes Y2 into Y1b region)
    gemm2_kernel<<<dim3(GB), dim3(256), 0, stream>>>(Hb, Wt2, b2, Y1b, N);

    // S4: agg2 (+log_softmax, fp32 out)
    agg2_kernel<<<dim3(NRANGE), dim3(512), 0, stream>>>(
        (const unsigned*)Y1b, ebuf, rangeLen, curv2, out, N);
}

// Round 6
// 217.839 us; speedup vs baseline: 5.4699x; 5.4699x over previous
//
#include <hip/hip_runtime.h>
#include <math.h>

// ---------------------------------------------------------------------------
// HGCN, 2 layers. softmax over size-1 axis == 1.0 -> attention branch dead.
//   Y = X@W + b  (bf16 MFMA, fp32 accum, bf16 store)
//   agg[n] = -|curv| * (Y[n] + sum_{dst(e)=n} Y[src(e)])  (bf16 gather,
//            fp32 register accumulate -- NO atomics on the per-edge path)
//   layer1 -> relu (bf16 h), layer2 -> log_softmax (fp32 out)
// 6 dispatches:
//   S0 prep: weight transpose->bf16, zero rangeLen
//   S1 scatter(196 blk) || gemm1(782 blk): edges bucketed into 196 fixed-cap
//      range slabs (packed ldst<<16|src)
//   S2 sortB(196 blk): per-range LDS counting sort -> ushort ssrc slabs +
//      nodeInfo[n] = (localStart<<16 | count)
//   S3 agg1(12500 blk): one wave/node gather, 8-unroll, relu, bf16 h
//   S4 gemm2(782 blk)
//   S5 agg2(12500 blk): half-wave/edge gather + fused log_softmax
// ---------------------------------------------------------------------------

#define NRANGE 196            // ceil(50000/256) node ranges of 256
#define RCAP   4608           // slab capacity; mean 4081, sd 64 -> +8 sigma

typedef float f32x4 __attribute__((ext_vector_type(4)));
typedef short bf16x8 __attribute__((ext_vector_type(8)));

__device__ inline ushort f2bf(float x) {
    unsigned u = __float_as_uint(x);
    return (ushort)((u + 0x7fffu + ((u >> 16) & 1u)) >> 16);
}
__device__ inline unsigned f2bf_pack(float a, float b) {
    return (unsigned)f2bf(a) | ((unsigned)f2bf(b) << 16);
}
__device__ inline float bflo(unsigned u) { return __uint_as_float(u << 16); }
__device__ inline float bfhi(unsigned u) { return __uint_as_float(u & 0xffff0000u); }

// ---------------- S0: weight prep + rangeLen zero --------------------------
__launch_bounds__(256)
__global__ void prep_kernel(const float* __restrict__ W1, const float* __restrict__ W2,
                            ushort* __restrict__ Wt1, ushort* __restrict__ Wt2,
                            int* __restrict__ rangeLen) {
    if (blockIdx.x == 0 && threadIdx.x < NRANGE) rangeLen[threadIdx.x] = 0;
    int t = blockIdx.x * 256 + threadIdx.x;
    if (t < 16384) {               // Wt1[c][k] = bf16(W1[k][c]), 128x128
        int c = t >> 7, k = t & 127;
        Wt1[t] = f2bf(W1[k * 128 + c]);
    } else if (t < 24576) {        // Wt2[c][k] = bf16(W2[k][c]), 64x128
        int i = t - 16384;
        int c = i >> 7, k = i & 127;
        Wt2[i] = f2bf(W2[k * 64 + c]);
    }
}

// ---------------- S1: fused edge-bucket scatter || gemm1 -------------------
__launch_bounds__(256)
__global__ void stage1_kernel(const int* __restrict__ src, const int* __restrict__ dst,
                              int* __restrict__ rangeLen, unsigned* __restrict__ ebuf, int E,
                              int scatterBlocks,
                              const float* __restrict__ X, const ushort* __restrict__ Wt,
                              const float* __restrict__ Bb, ushort* __restrict__ Y, int nrows) {
    __shared__ uint4 As[1024];            // gemm path (16 KB)
    __shared__ int sh_h[NRANGE];          // scatter path
    __shared__ int sh_base[NRANGE];
    const int t = threadIdx.x;

    if ((int)blockIdx.x < scatterBlocks) {
        // ---- edge bucket scatter: 4096 edges per block ----
        if (t < NRANGE) sh_h[t] = 0;
        __syncthreads();
        const int cbase = blockIdx.x * 4096;
        for (int i = t; i < 4096; i += 256) {
            int e = cbase + i;
            if (e < E) atomicAdd(&sh_h[dst[e] >> 8], 1);
        }
        __syncthreads();
        if (t < NRANGE) {
            int c = sh_h[t];
            sh_base[t] = c ? atomicAdd(&rangeLen[t], c) : 0;
            sh_h[t] = 0;
        }
        __syncthreads();
        for (int i = t; i < 4096; i += 256) {
            int e = cbase + i;
            if (e < E) {
                int d = dst[e];
                int r = d >> 8;
                int slot = sh_base[r] + atomicAdd(&sh_h[r], 1);
                ebuf[(size_t)r * RCAP + slot] = (unsigned)src[e] | ((unsigned)(d & 255) << 16);
            }
        }
        return;
    }

    // ---- gemm1: Y[64 rows x 128 cols] = bf16(X @ W1 + b1) ----
    const int rowBase = ((int)blockIdx.x - scatterBlocks) * 64;
#pragma unroll
    for (int i = 0; i < 4; ++i) {
        int s = i * 256 + t;
        int r = s >> 4, kb = s & 15;
        int grow = rowBase + r;
        float4 f0 = make_float4(0.f,0.f,0.f,0.f), f1 = f0;
        if (grow < nrows) {
            const float4* xp = (const float4*)(X + (size_t)grow * 128 + kb * 8);
            f0 = xp[0]; f1 = xp[1];
        }
        uint4 u;
        u.x = f2bf_pack(f0.x, f0.y); u.y = f2bf_pack(f0.z, f0.w);
        u.z = f2bf_pack(f1.x, f1.y); u.w = f2bf_pack(f1.z, f1.w);
        As[r * 16 + (kb ^ (r & 15))] = u;
    }
    __syncthreads();
    const int lane = t & 63, w = t >> 6;
    const int row = w * 16 + (lane & 15);
    const int lg = lane >> 4;
    f32x4 acc[8];
#pragma unroll
    for (int tc = 0; tc < 8; ++tc) acc[tc] = (f32x4){0.f, 0.f, 0.f, 0.f};
    const uint4* Wv = (const uint4*)Wt;
#pragma unroll
    for (int ks = 0; ks < 4; ++ks) {
        int kb = ks * 4 + lg;
        bf16x8 a = *(const bf16x8*)&As[row * 16 + (kb ^ (row & 15))];
#pragma unroll
        for (int tc = 0; tc < 8; ++tc) {
            int col = tc * 16 + (lane & 15);
            bf16x8 b = *(const bf16x8*)&Wv[col * 16 + kb];
            acc[tc] = __builtin_amdgcn_mfma_f32_16x16x32_bf16(a, b, acc[tc], 0, 0, 0);
        }
    }
#pragma unroll
    for (int tc = 0; tc < 8; ++tc) {
        int col = tc * 16 + (lane & 15);
        float bias = Bb[col];
#pragma unroll
        for (int e = 0; e < 4; ++e) {
            int grow = rowBase + w * 16 + lg * 4 + e;
            if (grow < nrows) Y[(size_t)grow * 128 + col] = f2bf(acc[tc][e] + bias);
        }
    }
}

// ---------------- S2: per-range counting sort ------------------------------
// slab (ldst<<16|src) -> node-sorted ushort ssrc slab + nodeInfo packed.
__launch_bounds__(256)
__global__ void sortB_kernel(const unsigned* __restrict__ ebuf, const int* __restrict__ rangeLen,
                             ushort* __restrict__ ssrcg, unsigned* __restrict__ nodeInfo,
                             int nnodes) {
    __shared__ int h[256];
    __shared__ int cur[256];
    __shared__ int ws[4];
    const int t = threadIdx.x, lane = t & 63, w = t >> 6;
    const int r = blockIdx.x;
    const int cnt = rangeLen[r];
    const unsigned* eb = ebuf + (size_t)r * RCAP;
    h[t] = 0;
    __syncthreads();
    for (int e = t; e < cnt; e += 256) atomicAdd(&h[eb[e] >> 16], 1);
    __syncthreads();
    int v = h[t];
    int incl = v;
#pragma unroll
    for (int d = 1; d < 64; d <<= 1) {
        int tmp = __shfl_up(incl, d);
        if (lane >= d) incl += tmp;
    }
    if (lane == 63) ws[w] = incl;
    __syncthreads();
    int off = 0;
    for (int k = 0; k < w; ++k) off += ws[k];
    int excl = off + incl - v;
    int node = (r << 8) + t;
    if (node < nnodes) nodeInfo[node] = ((unsigned)excl << 16) | (unsigned)v;
    cur[t] = excl;
    __syncthreads();
    ushort* sg = ssrcg + (size_t)r * RCAP;
    for (int e = t; e < cnt; e += 256) {
        unsigned p = eb[e];
        int s = atomicAdd(&cur[p >> 16], 1);
        sg[s] = (ushort)(p & 0xFFFFu);
    }
}

// ---------------- S3: agg1 — one wave/node gather + relu -------------------
__launch_bounds__(256)
__global__ void agg1_kernel(const unsigned* __restrict__ Yu,     // [N][64] uints
                            const unsigned* __restrict__ nodeInfo,
                            const ushort* __restrict__ ssrcg,
                            const float* __restrict__ curv,
                            unsigned* __restrict__ Hb,           // [N][64] uints
                            int nnodes) {
    const int wid = threadIdx.x >> 6, lane = threadIdx.x & 63;
    const int node = blockIdx.x * 4 + wid;
    if (node >= nnodes) return;
    unsigned u = Yu[(size_t)node * 64 + lane];
    float a0 = bflo(u), a1 = bfhi(u);
    float b0 = 0.f, b1 = 0.f, c0 = 0.f, c1 = 0.f, d0 = 0.f, d1 = 0.f;
    const unsigned info = nodeInfo[node];
    const ushort* sg = ssrcg + (size_t)(node >> 8) * RCAP + (info >> 16);
    const int cnt = (int)(info & 0xFFFFu);
    int j = 0;
    for (; j + 8 <= cnt; j += 8) {
        int sA = sg[j], sB = sg[j+1], sC = sg[j+2], sD = sg[j+3];
        int sE = sg[j+4], sF = sg[j+5], sG = sg[j+6], sH = sg[j+7];
        unsigned uA = Yu[(size_t)sA * 64 + lane];
        unsigned uB = Yu[(size_t)sB * 64 + lane];
        unsigned uC = Yu[(size_t)sC * 64 + lane];
        unsigned uD = Yu[(size_t)sD * 64 + lane];
        unsigned uE = Yu[(size_t)sE * 64 + lane];
        unsigned uF = Yu[(size_t)sF * 64 + lane];
        unsigned uG = Yu[(size_t)sG * 64 + lane];
        unsigned uH = Yu[(size_t)sH * 64 + lane];
        a0 += bflo(uA) + bflo(uB); a1 += bfhi(uA) + bfhi(uB);
        b0 += bflo(uC) + bflo(uD); b1 += bfhi(uC) + bfhi(uD);
        c0 += bflo(uE) + bflo(uF); c1 += bfhi(uE) + bfhi(uF);
        d0 += bflo(uG) + bflo(uH); d1 += bfhi(uG) + bfhi(uH);
    }
    for (; j < cnt; ++j) {
        unsigned uA = Yu[(size_t)sg[j] * 64 + lane];
        a0 += bflo(uA); a1 += bfhi(uA);
    }
    a0 += b0 + c0 + d0; a1 += b1 + c1 + d1;
    const float sc = -fabsf(curv[0]);
    a0 = fmaxf(a0 * sc, 0.f); a1 = fmaxf(a1 * sc, 0.f);
    Hb[(size_t)node * 64 + lane] = f2bf_pack(a0, a1);
}

// ---------------- S4: gemm2 ------------------------------------------------
__launch_bounds__(256)
__global__ void gemm2_kernel(const ushort* __restrict__ Hb, const ushort* __restrict__ Wt,
                             const float* __restrict__ Bb, ushort* __restrict__ Y, int nrows) {
    __shared__ uint4 As[1024];
    const int t = threadIdx.x;
    const int rowBase = blockIdx.x * 64;
    const uint4* Hv = (const uint4*)Hb;
#pragma unroll
    for (int i = 0; i < 4; ++i) {
        int s = i * 256 + t;
        int r = s >> 4, kb = s & 15;
        int grow = rowBase + r;
        uint4 u = make_uint4(0u, 0u, 0u, 0u);
        if (grow < nrows) u = Hv[(size_t)grow * 16 + kb];
        As[r * 16 + (kb ^ (r & 15))] = u;
    }
    __syncthreads();
    const int lane = t & 63, w = t >> 6;
    const int row = w * 16 + (lane & 15);
    const int lg = lane >> 4;
    f32x4 acc[4];
#pragma unroll
    for (int tc = 0; tc < 4; ++tc) acc[tc] = (f32x4){0.f, 0.f, 0.f, 0.f};
    const uint4* Wv = (const uint4*)Wt;
#pragma unroll
    for (int ks = 0; ks < 4; ++ks) {
        int kb = ks * 4 + lg;
        bf16x8 a = *(const bf16x8*)&As[row * 16 + (kb ^ (row & 15))];
#pragma unroll
        for (int tc = 0; tc < 4; ++tc) {
            int col = tc * 16 + (lane & 15);
            bf16x8 b = *(const bf16x8*)&Wv[col * 16 + kb];
            acc[tc] = __builtin_amdgcn_mfma_f32_16x16x32_bf16(a, b, acc[tc], 0, 0, 0);
        }
    }
#pragma unroll
    for (int tc = 0; tc < 4; ++tc) {
        int col = tc * 16 + (lane & 15);
        float bias = Bb[col];
#pragma unroll
        for (int e = 0; e < 4; ++e) {
            int grow = rowBase + w * 16 + lg * 4 + e;
            if (grow < nrows) Y[(size_t)grow * 64 + col] = f2bf(acc[tc][e] + bias);
        }
    }
}

// ---------------- S5: agg2 — half-wave/edge gather + log_softmax -----------
__launch_bounds__(256)
__global__ void agg2_kernel(const unsigned* __restrict__ Yu,     // [N][32] uints
                            const unsigned* __restrict__ nodeInfo,
                            const ushort* __restrict__ ssrcg,
                            const float* __restrict__ curv,
                            float* __restrict__ out, int nnodes) {
    const int wid = threadIdx.x >> 6, lane = threadIdx.x & 63;
    const int node = blockIdx.x * 4 + wid;
    if (node >= nnodes) return;
    const int half = lane >> 5, l2 = lane & 31;
    float a0 = 0.f, a1 = 0.f, b0 = 0.f, b1 = 0.f;
    if (half == 0) {
        unsigned u = Yu[(size_t)node * 32 + l2];
        a0 = bflo(u); a1 = bfhi(u);
    }
    const unsigned info = nodeInfo[node];
    const ushort* sg = ssrcg + (size_t)(node >> 8) * RCAP + (info >> 16);
    const int cnt = (int)(info & 0xFFFFu);
    int j = 0;
    for (; j + 16 <= cnt; j += 16) {
#pragma unroll
        for (int i = 0; i < 8; ++i) {
            int s = sg[j + 2 * i + half];
            unsigned u = Yu[(size_t)s * 32 + l2];
            if (i & 1) { b0 += bflo(u); b1 += bfhi(u); }
            else       { a0 += bflo(u); a1 += bfhi(u); }
        }
    }
    for (; j < cnt; j += 2) {
        int idx = j + half;
        if (idx < cnt) {
            unsigned u = Yu[(size_t)sg[idx] * 32 + l2];
            a0 += bflo(u); a1 += bfhi(u);
        }
    }
    a0 += b0; a1 += b1;
    a0 += __shfl_xor(a0, 32);
    a1 += __shfl_xor(a1, 32);
    const float sc = -fabsf(curv[0]);
    a0 *= sc; a1 *= sc;
    float m = fmaxf(a0, a1);
#pragma unroll
    for (int d = 16; d; d >>= 1) m = fmaxf(m, __shfl_xor(m, d));
    float s = expf(a0 - m) + expf(a1 - m);
#pragma unroll
    for (int d = 16; d; d >>= 1) s += __shfl_xor(s, d);
    float ls = logf(s);
    if (half == 0)
        *(float2*)(out + (size_t)node * 64 + 2 * l2) = make_float2(a0 - m - ls, a1 - m - ls);
}

// ---------------------------------------------------------------------------
extern "C" void kernel_launch(void* const* d_in, const int* in_sizes, int n_in,
                              void* d_out, int out_size, void* d_ws, size_t ws_size,
                              hipStream_t stream) {
    const float* x     = (const float*)d_in[0];
    const int*   ei    = (const int*)d_in[1];
    const float* W1    = (const float*)d_in[2];
    const float* b1    = (const float*)d_in[3];
    const float* curv1 = (const float*)d_in[6];
    const float* W2    = (const float*)d_in[7];
    const float* b2    = (const float*)d_in[8];
    const float* curv2 = (const float*)d_in[11];
    float* out = (float*)d_out;

    const int N = 50000;
    const int E = in_sizes[1] / 2;         // 800000
    const int* src = ei;
    const int* dst = ei + E;
    const int SB = (E + 4095) / 4096;      // 196 scatter blocks
    const int GB = (N + 63) / 64;          // 782 gemm blocks

    char* ws = (char*)d_ws;
    const size_t MB = 1024u * 1024u;
    ushort*   Y1b      = (ushort*)(ws);                    // bf16 [N,128] (reused as Y2 [N,64])
    ushort*   Hb       = (ushort*)(ws + 13 * MB);          // bf16 [N,128]
    unsigned* ebuf     = (unsigned*)(ws + 26 * MB);        // 196*4608*4B = 3.62 MB
    ushort*   ssrcg    = (ushort*)(ws + 30 * MB);          // 196*4608*2B = 1.81 MB
    unsigned* nodeInfo = (unsigned*)(ws + 32 * MB);        // N uints
    int*      rangeLen = (int*)(ws + 33 * MB);             // 196 ints
    ushort*   Wt1      = (ushort*)(ws + 33 * MB + 4096);   // 32 KB
    ushort*   Wt2      = (ushort*)(ws + 33 * MB + 4096 + 32768);  // 16 KB

    // S0: weight transpose + rangeLen zero
    prep_kernel<<<dim3(96), dim3(256), 0, stream>>>(W1, W2, Wt1, Wt2, rangeLen);

    // S1: edge bucket scatter || gemm1
    stage1_kernel<<<dim3(SB + GB), dim3(256), 0, stream>>>(
        src, dst, rangeLen, ebuf, E, SB, x, Wt1, b1, Y1b, N);

    // S2: per-range sort -> ushort ssrc + nodeInfo
    sortB_kernel<<<dim3(NRANGE), dim3(256), 0, stream>>>(ebuf, rangeLen, ssrcg, nodeInfo, N);

    // S3: agg1 (+relu, bf16 h)
    agg1_kernel<<<dim3((N + 3) / 4), dim3(256), 0, stream>>>(
        (const unsigned*)Y1b, nodeInfo, ssrcg, curv1, (unsigned*)Hb, N);

    // S4: gemm2 (writes Y2 into Y1b region)
    gemm2_kernel<<<dim3(GB), dim3(256), 0, stream>>>(Hb, Wt2, b2, Y1b, N);

    // S5: agg2 (+log_softmax, fp32 out)
    agg2_kernel<<<dim3((N + 3) / 4), dim3(256), 0, stream>>>(
        (const unsigned*)Y1b, nodeInfo, ssrcg, curv2, out, N);
}